// Round 2
// baseline (1754.990 us; speedup 1.0000x reference)
//
#include <hip/hip_runtime.h>
#include <hip/hip_bf16.h>

#define DI __device__ __forceinline__

typedef __attribute__((ext_vector_type(8))) short bf16x8;  // 8 bf16 (4 VGPRs)
typedef __attribute__((ext_vector_type(4))) float f32x4;
typedef unsigned short u16;

// float -> bf16 bits, round-to-nearest-even
DI u16 f2bf(float f) {
  union { float f; unsigned int u; } v; v.f = f;
  unsigned int r = v.u + 0x7fffu + ((v.u >> 16) & 1u);
  return (u16)(r >> 16);
}

// async global->LDS, 16B per lane (dest must be wave-uniform base + lane*16)
DI void gload16(const void* g, void* l) {
  __builtin_amdgcn_global_load_lds(
      (const __attribute__((address_space(1))) void*)g,
      (__attribute__((address_space(3))) void*)l, 16, 0, 0);
}

#define BARRIER   asm volatile("s_barrier" ::: "memory")
#define WAITLGKM0 asm volatile("s_waitcnt lgkmcnt(0)" ::: "memory")
#define WAITVM6   asm volatile("s_waitcnt vmcnt(6)" ::: "memory")
#define WAITVM4   asm volatile("s_waitcnt vmcnt(4)" ::: "memory")
#define WAITVM0   asm volatile("s_waitcnt vmcnt(0)" ::: "memory")
#define PRIO1     __builtin_amdgcn_s_setprio(1)
#define PRIO0     __builtin_amdgcn_s_setprio(0)

// ---------------- embedding + positional encoding ----------------
__global__ __launch_bounds__(256) void k_embed(const int* __restrict__ tokens,
    const float* __restrict__ emb, float* __restrict__ X, u16* __restrict__ Xb) {
  int t = blockIdx.x;              // 0..4095
  int s = t & 1023;
  int tok = tokens[t];
  int d = threadIdx.x * 4;
  float4 ev = *(const float4*)(emb + (size_t)tok * 1024 + d);
  const float C = 9.210340371976184f / 1024.f;   // ln(10000)/D
  float fs = (float)s;
  float a0 = fs * __expf(-((float)d) * C);
  float a2 = fs * __expf(-((float)(d + 2)) * C);
  float o0 = ev.x + sinf(a0);
  float o1 = ev.y + cosf(a0);
  float o2 = ev.z + sinf(a2);
  float o3 = ev.w + cosf(a2);
  *(float4*)(X + (size_t)t * 1024 + d) = make_float4(o0, o1, o2, o3);
  ushort4 ob; ob.x = f2bf(o0); ob.y = f2bf(o1); ob.z = f2bf(o2); ob.w = f2bf(o3);
  *(ushort4*)(Xb + (size_t)t * 1024 + d) = ob;
}

// ---------------- tiled transpose + fp32->bf16 cast (single) ----------------
__global__ __launch_bounds__(256) void k_tcast(const float* __restrict__ in,
    u16* __restrict__ out, int K, int N) {
  __shared__ float t[32][33];
  int n0 = blockIdx.x * 32, k0 = blockIdx.y * 32;
  int tx = threadIdx.x, ty = threadIdx.y;
#pragma unroll
  for (int j = 0; j < 32; j += 8)
    t[ty + j][tx] = in[(size_t)(k0 + ty + j) * N + n0 + tx];
  __syncthreads();
#pragma unroll
  for (int j = 0; j < 32; j += 8)
    out[(size_t)(n0 + ty + j) * K + k0 + tx] = f2bf(t[tx][ty + j]);
}

// ---------------- fused 4-weight transpose+cast (one dispatch/layer) --------
struct TC4 {
  const float* src[4];
  u16* dst[4];
  int K[4], N[4];
  int start[4];   // first linear tile index of each segment
};
__global__ __launch_bounds__(256) void k_tcast4(TC4 tc) {
  __shared__ float t[32][33];
  int bid = blockIdx.x;
  int s = (bid >= tc.start[1]) + (bid >= tc.start[2]) + (bid >= tc.start[3]);
  int rel = bid - tc.start[s];
  int K = tc.K[s], N = tc.N[s];
  int tilesX = N >> 5;
  int n0 = (rel % tilesX) * 32, k0 = (rel / tilesX) * 32;
  const float* in = tc.src[s];
  u16* out = tc.dst[s];
  int tx = threadIdx.x & 31, ty = threadIdx.x >> 5;
#pragma unroll
  for (int j = 0; j < 32; j += 8)
    t[ty + j][tx] = in[(size_t)(k0 + ty + j) * N + n0 + tx];
  __syncthreads();
#pragma unroll
  for (int j = 0; j < 32; j += 8)
    out[(size_t)(n0 + ty + j) * K + k0 + tx] = f2bf(t[tx][ty + j]);
}

// ---------------- 256x256 8-phase bf16 GEMM (T2+T3+T4+T5 template) ----------
// C = A[M,Ktot] @ BT[N,Ktot]^T + bias.  K = per-split length (mult of 128),
// Ktot = K * gridDim.z; split z writes slab C + z*cstride (f32); bias in z==0.
// flags: 1 = relu, 2 = bf16 out (gridDim.z==1 only).
__global__ __launch_bounds__(512, 2) void k_gemm256(const u16* __restrict__ A,
    const u16* __restrict__ BT, const float* __restrict__ bias, void* __restrict__ C,
    int M, int N, int K, size_t cstride, int flags) {
  __shared__ u16 lds[2][4][8192];   // [buf][A0,A1,B0,B1][16KB region]
  int tid = threadIdx.x;
  int w = tid >> 6, l = tid & 63;
  int lm = l & 15, lq = l >> 4;
  int wr = w >> 2, wcn = w & 3;          // wave -> (M half, N quarter)
  int bco = (wcn & 1) * 64;              // wave's col offset within B region
  int sw8 = (lq ^ ((lm >> 1) & 3)) * 8;  // swizzled read slot (elems)
  int z = blockIdx.z;
  size_t Ktot = (size_t)K * gridDim.z;
  size_t m0 = (size_t)blockIdx.x * 256;
  size_t n0 = (size_t)blockIdx.y * 256;
  const u16* gA = A + m0 * Ktot + (size_t)z * K;
  const u16* gB = BT + n0 * Ktot + (size_t)z * K;
  const u16* a0p = gA;
  const u16* a1p = gA + (size_t)128 * Ktot;
  const u16* b0p = gB;
  const u16* b1p = gB + (size_t)128 * Ktot;
  // staging: thread covers LDS 16B slots q0=tid (kh=0) and q1=tid+512 (kh=1);
  // global col chunk is inverse-swizzled so the swizzled READ sees logical data
  int q0 = tid, q1 = tid + 512;
  int srow = (q0 >> 2) & 127;
  int ssl = (q0 & 3) ^ ((srow >> 1) & 3);
  size_t go0 = (size_t)srow * Ktot + (size_t)(ssl * 8);        // kh=0
  size_t go1 = go0 + 32;                                       // kh=1 same row/slot
  u16* L0A0 = &lds[0][0][0]; u16* L0A1 = &lds[0][1][0];
  u16* L0B0 = &lds[0][2][0]; u16* L0B1 = &lds[0][3][0];
  u16* L1A0 = &lds[1][0][0]; u16* L1A1 = &lds[1][1][0];
  u16* L1B0 = &lds[1][2][0]; u16* L1B1 = &lds[1][3][0];
#define STG(gp, lp) do { gload16((gp) + go0, (lp) + q0 * 8); \
                         gload16((gp) + go1, (lp) + q1 * 8); } while (0)

  f32x4 acc[8][4];
#pragma unroll
  for (int mi = 0; mi < 8; mi++)
#pragma unroll
    for (int ni = 0; ni < 4; ni++) acc[mi][ni] = (f32x4){0.f, 0.f, 0.f, 0.f};
  bf16x8 af[4][2], bfr[4][2];

#define RDA(b, mh) do { const u16* _R = &lds[b][wr][0];                        \
  _Pragma("unroll") for (int mf = 0; mf < 4; mf++) {                           \
    int _row = (mh) * 64 + mf * 16 + lm;                                       \
    _Pragma("unroll") for (int kh = 0; kh < 2; kh++)                           \
      af[mf][kh] = *(const bf16x8*)&_R[(kh * 128 + _row) * 32 + sw8];          \
  } } while (0)
#define RDB(b) do { const u16* _R = &lds[b][2 + (wcn >> 1)][0];                \
  _Pragma("unroll") for (int nf = 0; nf < 4; nf++) {                           \
    int _row = bco + nf * 16 + lm;                                             \
    _Pragma("unroll") for (int kh = 0; kh < 2; kh++)                           \
      bfr[nf][kh] = *(const bf16x8*)&_R[(kh * 128 + _row) * 32 + sw8];         \
  } } while (0)
#define MM(mh, nh) do {                                                        \
  _Pragma("unroll") for (int mf = 0; mf < 4; mf++)                             \
    _Pragma("unroll") for (int nf = 0; nf < 2; nf++)                           \
      _Pragma("unroll") for (int kh = 0; kh < 2; kh++)                         \
        acc[(mh) * 4 + mf][(nh) * 2 + nf] =                                    \
            __builtin_amdgcn_mfma_f32_16x16x32_bf16(af[mf][kh],                \
                bfr[(nh) * 2 + nf][kh], acc[(mh) * 4 + mf][(nh) * 2 + nf],     \
                0, 0, 0);                                                      \
  } while (0)

  // prologue: tile0 {B0,B1,A0,A1}, tile1 {B0,B1,A0}; vmcnt(6) lands tile0
  STG(b0p + 0 * 64, L0B0);
  STG(b1p + 0 * 64, L0B1);
  STG(a0p + 0 * 64, L0A0);
  STG(a1p + 0 * 64, L0A1);
  STG(b0p + 1 * 64, L1B0);
  STG(b1p + 1 * 64, L1B1);
  STG(a0p + 1 * 64, L1A0);
  WAITVM6; BARRIER;

#define KBODY(kt0, LAST_)                                                      \
  {                                                                            \
    int _ktA = (kt0) + 2, _ktB = (kt0) + 3;                                    \
    /* ph1: tile kt0 Q(M0,N0); stage this pair's odd-tile A1 */                \
    RDA(0, 0); RDB(0);                                                         \
    STG(a1p + (size_t)((kt0) + 1) * 64, L1A1);                                 \
    BARRIER; WAITLGKM0; PRIO1; MM(0, 0); PRIO0; BARRIER;                       \
    /* ph2 */                                                                  \
    if (!(LAST_)) STG(b0p + (size_t)_ktA * 64, L0B0);                          \
    BARRIER; PRIO1; MM(0, 1); PRIO0; BARRIER;                                  \
    /* ph3 */                                                                  \
    RDA(0, 1);                                                                 \
    if (!(LAST_)) STG(b1p + (size_t)_ktA * 64, L0B1);                          \
    BARRIER; WAITLGKM0; PRIO1; MM(1, 0); PRIO0; BARRIER;                       \
    /* ph4: counted vmcnt -> buf1 fully landed for ph5-7 */                    \
    if (LAST_) { WAITVM0; }                                                    \
    else       { STG(a0p + (size_t)_ktA * 64, L0A0); WAITVM6; }                \
    BARRIER; PRIO1; MM(1, 1); PRIO0; BARRIER;                                  \
    /* ph5: tile kt0+1 */                                                      \
    RDA(1, 0); RDB(1);                                                         \
    if (!(LAST_)) STG(a1p + (size_t)_ktA * 64, L0A1);                          \
    BARRIER; WAITLGKM0; PRIO1; MM(0, 0); PRIO0; BARRIER;                       \
    /* ph6 */                                                                  \
    if (!(LAST_)) STG(b0p + (size_t)_ktB * 64, L1B0);                          \
    BARRIER; PRIO1; MM(0, 1); PRIO0; BARRIER;                                  \
    /* ph7 */                                                                  \
    RDA(1, 1);                                                                 \
    if (!(LAST_)) STG(b1p + (size_t)_ktB * 64, L1B1);                          \
    BARRIER; WAITLGKM0; PRIO1; MM(1, 0); PRIO0; BARRIER;                       \
    /* ph8: counted vmcnt -> buf0 refills landed for next ph1 */               \
    if (!(LAST_)) { STG(a0p + (size_t)_ktB * 64, L1A0); WAITVM6; }             \
    BARRIER; PRIO1; MM(1, 1); PRIO0; BARRIER;                                  \
  }

  int NIT = K >> 7;   // K/128 double-tile iterations (K % 128 == 0)
  for (int i = 0; i < NIT - 1; i++) KBODY(2 * i, 0);
  KBODY(2 * (NIT - 1), 1);
#undef KBODY
#undef MM
#undef RDB
#undef RDA
#undef STG

  // epilogue: C/D layout col=lane&15, row=(lane>>4)*4+reg
  float* Cf = (float*)C + (size_t)z * cstride;
#pragma unroll
  for (int ni = 0; ni < 4; ni++) {
    size_t col = n0 + (size_t)wcn * 64 + ni * 16 + lm;
    float bv = (z == 0) ? bias[col] : 0.f;
#pragma unroll
    for (int mi = 0; mi < 8; mi++)
#pragma unroll
      for (int j = 0; j < 4; j++) {
        size_t row = m0 + (size_t)wr * 128 + mi * 16 + lq * 4 + j;
        float v = acc[mi][ni][j] + bv;
        if (flags & 1) v = fmaxf(v, 0.f);
        if (flags & 2) ((u16*)C)[row * N + col] = f2bf(v);
        else Cf[row * N + col] = v;
      }
  }
}

// ---------------- extract V^T per head: vt[head][d][t] ----------------
__global__ __launch_bounds__(256) void k_vt(const u16* __restrict__ qkv, u16* __restrict__ vt) {
  int head = blockIdx.x;               // b*16+h
  int b = head >> 4, h = head & 15;
  int t0 = blockIdx.y * 64;
  int tid = threadIdx.x;
  __shared__ u16 tile[64][66];
  int c = tid & 63, rr = tid >> 6;
#pragma unroll
  for (int r = 0; r < 16; r++) {
    int tt = r * 4 + rr;
    tile[tt][c] = qkv[(size_t)(b * 1024 + t0 + tt) * 3072 + h * 192 + 128 + c];
  }
  __syncthreads();
#pragma unroll
  for (int r = 0; r < 16; r++) {
    int dd = r * 4 + rr;
    vt[(size_t)head * 65536 + (size_t)dd * 1024 + t0 + c] = tile[c][dd];
  }
}

// ---------------- flash attention, fixed-shift streaming softmax ----------------
// Double-buffered K/V staging (T3/T4-lite): stage tile t+1 BEFORE computing
// tile t; counted s_waitcnt vmcnt(4) keeps the 4 newest gload_lds in flight
// across both barriers (never drain to 0 in the loop).  WAR on buf[cur^1]
// (read at tile t-1) is protected by the end-of-tile barrier; RAW on tile t
// by vmcnt(4) + top barrier.  setprio(1) wraps MFMA clusters (T5).
__global__ __launch_bounds__(256) void k_attn(const u16* __restrict__ qkv,
    const u16* __restrict__ vt, u16* __restrict__ vals) {
  int head = blockIdx.x;
  int b = head >> 4, h = head & 15;
  int qb = blockIdx.y;
  int tid = threadIdx.x, w = tid >> 6, l = tid & 63;
  int lm = l & 15, lq = l >> 4;
  __shared__ u16 Ks[2][2][64][32];   // [buf][kh][t][32]
  __shared__ u16 Vs[2][2][64][32];
  __shared__ u16 Ps[4][16][72];
  int q0 = qb * 64 + w * 16;
  const u16* qp = qkv + (size_t)(b * 1024 + q0 + lm) * 3072 + h * 192 + lq * 8;
  bf16x8 qf0 = *(const bf16x8*)qp;
  bf16x8 qf1 = *(const bf16x8*)(qp + 32);
  f32x4 of[4];
#pragma unroll
  for (int d = 0; d < 4; d++) of[d] = (f32x4){0.f, 0.f, 0.f, 0.f};
  float lrow[4] = {0.f, 0.f, 0.f, 0.f};
  int srow = w * 16 + (l >> 2);
  int sch = (l & 3) * 8;
  const u16* gk = qkv + (size_t)(b * 1024 + srow) * 3072 + h * 192 + 64 + sch;
  const u16* gv = vt + (size_t)head * 65536 + (size_t)srow * 1024 + sch;
  const float CEXP = 0.18033688011112042f;   // log2(e) / sqrt(64)
#define ASTG(c, t0) do {                                                \
    u16* lk_ = &Ks[c][0][0][0] + w * 512 + l * 8;                       \
    u16* lv_ = &Vs[c][0][0][0] + w * 512 + l * 8;                       \
    gload16(gk + (size_t)(t0) * 3072, lk_);                             \
    gload16(gk + (size_t)(t0) * 3072 + 32, lk_ + 64 * 32);              \
    gload16(gv + (t0), lv_);                                            \
    gload16(gv + (t0) + 32, lv_ + 64 * 32);                             \
  } while (0)
  ASTG(0, 0);
  for (int it = 0; it < 16; ++it) {
    int cur = it & 1;
    if (it < 15) { ASTG(cur ^ 1, (it + 1) * 64); WAITVM4; }
    else         { WAITVM0; }
    BARRIER;
#pragma unroll
    for (int c = 0; c < 4; c++) {
      bf16x8 k0f = *(const bf16x8*)&Ks[cur][0][c * 16 + lm][lq * 8];
      bf16x8 k1f = *(const bf16x8*)&Ks[cur][1][c * 16 + lm][lq * 8];
      f32x4 z = (f32x4){0.f, 0.f, 0.f, 0.f};
      PRIO1;
      z = __builtin_amdgcn_mfma_f32_16x16x32_bf16(qf0, k0f, z, 0, 0, 0);
      z = __builtin_amdgcn_mfma_f32_16x16x32_bf16(qf1, k1f, z, 0, 0, 0);
      PRIO0;
#pragma unroll
      for (int j = 0; j < 4; j++) {
        float p = __builtin_amdgcn_exp2f(z[j] * CEXP);
        lrow[j] += p;
        Ps[w][lq * 4 + j][c * 16 + lm] = f2bf(p);
      }
    }
    // Ps is wave-private: intra-wave LDS ordering needs no barrier
    bf16x8 pa0 = *(const bf16x8*)&Ps[w][lm][lq * 8];
    bf16x8 pa1 = *(const bf16x8*)&Ps[w][lm][32 + lq * 8];
    PRIO1;
#pragma unroll
    for (int d = 0; d < 4; d++) {
      bf16x8 v0 = *(const bf16x8*)&Vs[cur][0][d * 16 + lm][lq * 8];
      bf16x8 v1 = *(const bf16x8*)&Vs[cur][1][d * 16 + lm][lq * 8];
      of[d] = __builtin_amdgcn_mfma_f32_16x16x32_bf16(pa0, v0, of[d], 0, 0, 0);
      of[d] = __builtin_amdgcn_mfma_f32_16x16x32_bf16(pa1, v1, of[d], 0, 0, 0);
    }
    PRIO0;
    BARRIER;   // all waves done reading buf[cur] before next-iter stage
  }
#undef ASTG
#pragma unroll
  for (int j = 0; j < 4; j++) {
#pragma unroll
    for (int off = 1; off < 16; off <<= 1) lrow[j] += __shfl_xor(lrow[j], off);
    lrow[j] = 1.f / lrow[j];
  }
#pragma unroll
  for (int d = 0; d < 4; d++)
#pragma unroll
    for (int j = 0; j < 4; j++) {
      int q = q0 + lq * 4 + j;
      vals[(size_t)(b * 1024 + q) * 1024 + h * 64 + d * 16 + lm] =
          f2bf(of[d][j] * lrow[j]);
    }
}

// ---------------- fused residual add (multi-slab) + LayerNorm ----------------
__global__ __launch_bounds__(256) void k_addln(const float* __restrict__ X,
    const float* __restrict__ Y, int nY, size_t ystr,
    const float* __restrict__ gamma, const float* __restrict__ beta,
    float* __restrict__ Xo, u16* __restrict__ Xb) {
  int row = blockIdx.x, tid = threadIdx.x;
  int w = tid >> 6, l = tid & 63;
  int d = tid * 4;
  float4 xv = *(const float4*)(X + (size_t)row * 1024 + d);
  float v0 = xv.x, v1 = xv.y, v2 = xv.z, v3 = xv.w;
  for (int y = 0; y < nY; y++) {
    float4 yv = *(const float4*)(Y + (size_t)y * ystr + (size_t)row * 1024 + d);
    v0 += yv.x; v1 += yv.y; v2 += yv.z; v3 += yv.w;
  }
  float s1 = v0 + v1 + v2 + v3;
  float s2 = v0 * v0 + v1 * v1 + v2 * v2 + v3 * v3;
#pragma unroll
  for (int off = 32; off; off >>= 1) {
    s1 += __shfl_xor(s1, off);
    s2 += __shfl_xor(s2, off);
  }
  __shared__ float red[8];
  if (l == 0) { red[w] = s1; red[4 + w] = s2; }
  __syncthreads();
  s1 = red[0] + red[1] + red[2] + red[3];
  s2 = red[4] + red[5] + red[6] + red[7];
  float mean = s1 * (1.f / 1024.f);
  float var = s2 * (1.f / 1024.f) - mean * mean;
  float rstd = rsqrtf(var + 1e-5f);
  float4 gv = *(const float4*)(gamma + d);
  float4 bv = *(const float4*)(beta + d);
  float o0 = gv.x * (v0 - mean) * rstd + bv.x;
  float o1 = gv.y * (v1 - mean) * rstd + bv.y;
  float o2 = gv.z * (v2 - mean) * rstd + bv.z;
  float o3 = gv.w * (v3 - mean) * rstd + bv.w;
  *(float4*)(Xo + (size_t)row * 1024 + d) = make_float4(o0, o1, o2, o3);
  ushort4 ob; ob.x = f2bf(o0); ob.y = f2bf(o1); ob.z = f2bf(o2); ob.w = f2bf(o3);
  *(ushort4*)(Xb + (size_t)row * 1024 + d) = ob;
}

extern "C" void kernel_launch(void* const* d_in, const int* in_sizes, int n_in,
                              void* d_out, int out_size, void* d_ws, size_t ws_size,
                              hipStream_t stream) {
  const int* tokens  = (const int*)d_in[0];
  const float* emb   = (const float*)d_in[2];
  const float* qkv_w = (const float*)d_in[3];
  const float* qkv_b = (const float*)d_in[4];
  const float* out_w = (const float*)d_in[5];
  const float* out_b = (const float*)d_in[6];
  const float* w1    = (const float*)d_in[7];
  const float* b1    = (const float*)d_in[8];
  const float* w2    = (const float*)d_in[9];
  const float* b2    = (const float*)d_in[10];
  const float* gamma = (const float*)d_in[11];
  const float* beta  = (const float*)d_in[12];

  const size_t MN = (size_t)4096 * 1024;          // elements of one [4096,1024] slab
  bool bigws = ws_size >= (size_t)158334976;

  char* p = (char*)d_ws;
  float* X; u16* Xb; float* Y; u16 *QKV, *VALS, *H1, *VT, *WB;
  u16 *WqkvT, *WoutT, *W1T, *W2T;
  int SPLIT_FFN, SPLIT_OUT;
  if (bigws) {
    X    = (float*)p; p += MN * 4;
    Xb   = (u16*)p;   p += MN * 2;
    H1   = (u16*)p;   p += (size_t)4096 * 4096 * 2;
    Y    = (float*)p; p += MN * 4;                       // Y0
    QKV  = (u16*)p;   p += (size_t)4096 * 3072 * 2;      // Y1,Y2 overlay
    VALS = (u16*)p;   p += MN * 2;                       // Y2 tail overlay
    VT   = (u16*)p;   p += (size_t)64 * 64 * 1024 * 2;   // Y3 overlay
    p += MN * 2;                                         // pad (Y3 tail)
    WB   = (u16*)p;   p += (size_t)12288 * 1024 * 2;     // 4 transposed weights
    WqkvT = WB;
    WoutT = WB + (size_t)3072 * 1024;
    W1T   = WoutT + (size_t)1024 * 1024;
    W2T   = W1T + (size_t)4096 * 1024;
    SPLIT_FFN = 4; SPLIT_OUT = 2;
  } else {
    X    = (float*)p; p += MN * 4;
    Xb   = (u16*)p;   p += MN * 2;
    Y    = (float*)p; p += MN * 4;
    QKV  = (u16*)p;   p += (size_t)4096 * 3072 * 2;
    VALS = (u16*)p;   p += MN * 2;
    H1   = (u16*)p;   p += (size_t)4096 * 4096 * 2;
    VT   = (u16*)p;   p += (size_t)64 * 64 * 1024 * 2;
    WB   = (u16*)p;   p += MN * 2;
    WqkvT = WoutT = W1T = W2T = WB;
    SPLIT_FFN = 2; SPLIT_OUT = 2;
  }

  k_embed<<<4096, 256, 0, stream>>>(tokens, emb, X, Xb);
  for (int i = 0; i < 6; i++) {
    if (bigws) {
      TC4 tc;
      tc.src[0] = qkv_w + (size_t)i * 1024 * 3072; tc.dst[0] = WqkvT;
      tc.K[0] = 1024; tc.N[0] = 3072; tc.start[0] = 0;
      tc.src[1] = out_w + (size_t)i * 1024 * 1024; tc.dst[1] = WoutT;
      tc.K[1] = 1024; tc.N[1] = 1024; tc.start[1] = 3072;
      tc.src[2] = w1 + (size_t)i * 1024 * 4096;    tc.dst[2] = W1T;
      tc.K[2] = 1024; tc.N[2] = 4096; tc.start[2] = 4096;
      tc.src[3] = w2 + (size_t)i * 4096 * 1024;    tc.dst[3] = W2T;
      tc.K[3] = 4096; tc.N[3] = 1024; tc.start[3] = 8192;
      k_tcast4<<<12288, 256, 0, stream>>>(tc);
    } else {
      k_tcast<<<dim3(96, 32), dim3(32, 8), 0, stream>>>(
          qkv_w + (size_t)i * 1024 * 3072, WqkvT, 1024, 3072);
    }
    // QKV projection
    k_gemm256<<<dim3(16, 12, 1), 512, 0, stream>>>(Xb, WqkvT, qkv_b + i * 3072, QKV,
                                                   4096, 3072, 1024, 0, 2);
    // attention
    k_vt<<<dim3(64, 16), 256, 0, stream>>>(QKV, VT);
    k_attn<<<dim3(64, 16), 256, 0, stream>>>(QKV, VT, VALS);
    // output projection (split-K) + add+LN
    if (!bigws)
      k_tcast<<<dim3(32, 32), dim3(32, 8), 0, stream>>>(
          out_w + (size_t)i * 1024 * 1024, WoutT, 1024, 1024);
    k_gemm256<<<dim3(16, 4, SPLIT_OUT), 512, 0, stream>>>(
        VALS, WoutT, out_b + i * 1024, Y, 4096, 1024, 1024 / SPLIT_OUT, MN, 0);
    k_addln<<<4096, 256, 0, stream>>>(X, Y, SPLIT_OUT, MN,
                                      gamma + i * 1024, beta + i * 1024, X, Xb);
    // FFN
    if (!bigws)
      k_tcast<<<dim3(128, 32), dim3(32, 8), 0, stream>>>(
          w1 + (size_t)i * 1024 * 4096, W1T, 1024, 4096);
    k_gemm256<<<dim3(16, 16, 1), 512, 0, stream>>>(Xb, W1T, b1 + i * 4096, H1,
                                                   4096, 4096, 1024, 0, 2 | 1);
    if (!bigws)
      k_tcast<<<dim3(32, 128), dim3(32, 8), 0, stream>>>(
          w2 + (size_t)i * 4096 * 1024, W2T, 4096, 1024);
    k_gemm256<<<dim3(16, 4, SPLIT_FFN), 512, 0, stream>>>(
        H1, W2T, b2 + i * 1024, Y, 4096, 1024, 4096 / SPLIT_FFN, MN, 0);
    float* xdst = (i == 5) ? (float*)d_out : X;
    k_addln<<<4096, 256, 0, stream>>>(X, Y, SPLIT_FFN, MN,
                                      gamma + i * 1024, beta + i * 1024, xdst, Xb);
  }
}

// Round 3
// 1583.538 us; speedup vs baseline: 1.1083x; 1.1083x over previous
//
#include <hip/hip_runtime.h>
#include <hip/hip_bf16.h>

#define DI __device__ __forceinline__

typedef __attribute__((ext_vector_type(8))) short bf16x8;  // 8 bf16 (4 VGPRs)
typedef __attribute__((ext_vector_type(4))) float f32x4;
typedef unsigned short u16;

// float -> bf16 bits, round-to-nearest-even
DI u16 f2bf(float f) {
  union { float f; unsigned int u; } v; v.f = f;
  unsigned int r = v.u + 0x7fffu + ((v.u >> 16) & 1u);
  return (u16)(r >> 16);
}

// async global->LDS, 16B per lane (dest must be wave-uniform base + lane*16)
DI void gload16(const void* g, void* l) {
  __builtin_amdgcn_global_load_lds(
      (const __attribute__((address_space(1))) void*)g,
      (__attribute__((address_space(3))) void*)l, 16, 0, 0);
}

#define BARRIER   asm volatile("s_barrier" ::: "memory")
#define WAITLGKM0 asm volatile("s_waitcnt lgkmcnt(0)" ::: "memory")
#define WAITVM6   asm volatile("s_waitcnt vmcnt(6)" ::: "memory")
#define WAITVM0   asm volatile("s_waitcnt vmcnt(0)" ::: "memory")
#define PRIO1     __builtin_amdgcn_s_setprio(1)
#define PRIO0     __builtin_amdgcn_s_setprio(0)

// ---------------- embedding + positional encoding ----------------
__global__ __launch_bounds__(256) void k_embed(const int* __restrict__ tokens,
    const float* __restrict__ emb, float* __restrict__ X, u16* __restrict__ Xb) {
  int t = blockIdx.x;              // 0..4095
  int s = t & 1023;
  int tok = tokens[t];
  int d = threadIdx.x * 4;
  float4 ev = *(const float4*)(emb + (size_t)tok * 1024 + d);
  const float C = 9.210340371976184f / 1024.f;   // ln(10000)/D
  float fs = (float)s;
  float a0 = fs * __expf(-((float)d) * C);
  float a2 = fs * __expf(-((float)(d + 2)) * C);
  float o0 = ev.x + sinf(a0);
  float o1 = ev.y + cosf(a0);
  float o2 = ev.z + sinf(a2);
  float o3 = ev.w + cosf(a2);
  *(float4*)(X + (size_t)t * 1024 + d) = make_float4(o0, o1, o2, o3);
  ushort4 ob; ob.x = f2bf(o0); ob.y = f2bf(o1); ob.z = f2bf(o2); ob.w = f2bf(o3);
  *(ushort4*)(Xb + (size_t)t * 1024 + d) = ob;
}

// ---------------- tiled transpose + fp32->bf16 cast (single) ----------------
__global__ __launch_bounds__(256) void k_tcast(const float* __restrict__ in,
    u16* __restrict__ out, int K, int N) {
  __shared__ float t[32][33];
  int n0 = blockIdx.x * 32, k0 = blockIdx.y * 32;
  int tx = threadIdx.x, ty = threadIdx.y;
#pragma unroll
  for (int j = 0; j < 32; j += 8)
    t[ty + j][tx] = in[(size_t)(k0 + ty + j) * N + n0 + tx];
  __syncthreads();
#pragma unroll
  for (int j = 0; j < 32; j += 8)
    out[(size_t)(n0 + ty + j) * K + k0 + tx] = f2bf(t[tx][ty + j]);
}

// ---------------- fused 4-weight transpose+cast (one dispatch/layer) --------
struct TC4 {
  const float* src[4];
  u16* dst[4];
  int K[4], N[4];
  int start[4];   // first linear tile index of each segment
};
__global__ __launch_bounds__(256) void k_tcast4(TC4 tc) {
  __shared__ float t[32][33];
  int bid = blockIdx.x;
  int s = (bid >= tc.start[1]) + (bid >= tc.start[2]) + (bid >= tc.start[3]);
  int rel = bid - tc.start[s];
  int K = tc.K[s], N = tc.N[s];
  int tilesX = N >> 5;
  int n0 = (rel % tilesX) * 32, k0 = (rel / tilesX) * 32;
  const float* in = tc.src[s];
  u16* out = tc.dst[s];
  int tx = threadIdx.x & 31, ty = threadIdx.x >> 5;
#pragma unroll
  for (int j = 0; j < 32; j += 8)
    t[ty + j][tx] = in[(size_t)(k0 + ty + j) * N + n0 + tx];
  __syncthreads();
#pragma unroll
  for (int j = 0; j < 32; j += 8)
    out[(size_t)(n0 + ty + j) * K + k0 + tx] = f2bf(t[tx][ty + j]);
}

// ---------------- 256x256 8-phase bf16 GEMM (T2+T3+T4+T5 template) ----------
// C = A[M,Ktot] @ BT[N,Ktot]^T + bias.  K = per-split length (mult of 128),
// Ktot = K * gridDim.z; split z writes slab C + z*cstride (f32); bias in z==0.
// flags: 1 = relu, 2 = bf16 out (gridDim.z==1 only).
// Epilogue: per-wave 16KB LDS repack (regions are dead after the loop) ->
// coalesced 1KB/wave-instr global_store_dwordx4, no partial-line RMW.
__global__ __launch_bounds__(512, 2) void k_gemm256(const u16* __restrict__ A,
    const u16* __restrict__ BT, const float* __restrict__ bias, void* __restrict__ C,
    int M, int N, int K, size_t cstride, int flags) {
  __shared__ u16 lds[2][4][8192];   // [buf][A0,A1,B0,B1][16KB region]
  int tid = threadIdx.x;
  int w = tid >> 6, l = tid & 63;
  int lm = l & 15, lq = l >> 4;
  int wr = w >> 2, wcn = w & 3;          // wave -> (M half, N quarter)
  int bco = (wcn & 1) * 64;              // wave's col offset within B region
  int sw8 = (lq ^ ((lm >> 1) & 3)) * 8;  // swizzled read slot (elems)
  int z = blockIdx.z;
  size_t Ktot = (size_t)K * gridDim.z;
  size_t m0 = (size_t)blockIdx.x * 256;
  size_t n0 = (size_t)blockIdx.y * 256;
  const u16* gA = A + m0 * Ktot + (size_t)z * K;
  const u16* gB = BT + n0 * Ktot + (size_t)z * K;
  const u16* a0p = gA;
  const u16* a1p = gA + (size_t)128 * Ktot;
  const u16* b0p = gB;
  const u16* b1p = gB + (size_t)128 * Ktot;
  // staging: thread covers LDS 16B slots q0=tid (kh=0) and q1=tid+512 (kh=1);
  // global col chunk is inverse-swizzled so the swizzled READ sees logical data
  int q0 = tid, q1 = tid + 512;
  int srow = (q0 >> 2) & 127;
  int ssl = (q0 & 3) ^ ((srow >> 1) & 3);
  size_t go0 = (size_t)srow * Ktot + (size_t)(ssl * 8);        // kh=0
  size_t go1 = go0 + 32;                                       // kh=1 same row/slot
  u16* L0A0 = &lds[0][0][0]; u16* L0A1 = &lds[0][1][0];
  u16* L0B0 = &lds[0][2][0]; u16* L0B1 = &lds[0][3][0];
  u16* L1A0 = &lds[1][0][0]; u16* L1A1 = &lds[1][1][0];
  u16* L1B0 = &lds[1][2][0]; u16* L1B1 = &lds[1][3][0];
#define STG(gp, lp) do { gload16((gp) + go0, (lp) + q0 * 8); \
                         gload16((gp) + go1, (lp) + q1 * 8); } while (0)

  f32x4 acc[8][4];
#pragma unroll
  for (int mi = 0; mi < 8; mi++)
#pragma unroll
    for (int ni = 0; ni < 4; ni++) acc[mi][ni] = (f32x4){0.f, 0.f, 0.f, 0.f};
  bf16x8 af[4][2], bfr[4][2];

#define RDA(b, mh) do { const u16* _R = &lds[b][wr][0];                        \
  _Pragma("unroll") for (int mf = 0; mf < 4; mf++) {                           \
    int _row = (mh) * 64 + mf * 16 + lm;                                       \
    _Pragma("unroll") for (int kh = 0; kh < 2; kh++)                           \
      af[mf][kh] = *(const bf16x8*)&_R[(kh * 128 + _row) * 32 + sw8];          \
  } } while (0)
#define RDB(b) do { const u16* _R = &lds[b][2 + (wcn >> 1)][0];                \
  _Pragma("unroll") for (int nf = 0; nf < 4; nf++) {                           \
    int _row = bco + nf * 16 + lm;                                             \
    _Pragma("unroll") for (int kh = 0; kh < 2; kh++)                           \
      bfr[nf][kh] = *(const bf16x8*)&_R[(kh * 128 + _row) * 32 + sw8];         \
  } } while (0)
#define MM(mh, nh) do {                                                        \
  _Pragma("unroll") for (int mf = 0; mf < 4; mf++)                             \
    _Pragma("unroll") for (int nf = 0; nf < 2; nf++)                           \
      _Pragma("unroll") for (int kh = 0; kh < 2; kh++)                         \
        acc[(mh) * 4 + mf][(nh) * 2 + nf] =                                    \
            __builtin_amdgcn_mfma_f32_16x16x32_bf16(af[mf][kh],                \
                bfr[(nh) * 2 + nf][kh], acc[(mh) * 4 + mf][(nh) * 2 + nf],     \
                0, 0, 0);                                                      \
  } while (0)

  // prologue: tile0 {B0,B1,A0,A1}, tile1 {B0,B1,A0}; vmcnt(6) lands tile0
  STG(b0p + 0 * 64, L0B0);
  STG(b1p + 0 * 64, L0B1);
  STG(a0p + 0 * 64, L0A0);
  STG(a1p + 0 * 64, L0A1);
  STG(b0p + 1 * 64, L1B0);
  STG(b1p + 1 * 64, L1B1);
  STG(a0p + 1 * 64, L1A0);
  WAITVM6; BARRIER;

#define KBODY(kt0, LAST_)                                                      \
  {                                                                            \
    int _ktA = (kt0) + 2, _ktB = (kt0) + 3;                                    \
    /* ph1: tile kt0 Q(M0,N0); stage this pair's odd-tile A1 */                \
    RDA(0, 0); RDB(0);                                                         \
    STG(a1p + (size_t)((kt0) + 1) * 64, L1A1);                                 \
    BARRIER; WAITLGKM0; PRIO1; MM(0, 0); PRIO0; BARRIER;                       \
    /* ph2 */                                                                  \
    if (!(LAST_)) STG(b0p + (size_t)_ktA * 64, L0B0);                          \
    BARRIER; PRIO1; MM(0, 1); PRIO0; BARRIER;                                  \
    /* ph3 */                                                                  \
    RDA(0, 1);                                                                 \
    if (!(LAST_)) STG(b1p + (size_t)_ktA * 64, L0B1);                          \
    BARRIER; WAITLGKM0; PRIO1; MM(1, 0); PRIO0; BARRIER;                       \
    /* ph4: counted vmcnt -> buf1 fully landed for ph5-7 */                    \
    if (LAST_) { WAITVM0; }                                                    \
    else       { STG(a0p + (size_t)_ktA * 64, L0A0); WAITVM6; }                \
    BARRIER; PRIO1; MM(1, 1); PRIO0; BARRIER;                                  \
    /* ph5: tile kt0+1 */                                                      \
    RDA(1, 0); RDB(1);                                                         \
    if (!(LAST_)) STG(a1p + (size_t)_ktA * 64, L0A1);                          \
    BARRIER; WAITLGKM0; PRIO1; MM(0, 0); PRIO0; BARRIER;                       \
    /* ph6 */                                                                  \
    if (!(LAST_)) STG(b0p + (size_t)_ktB * 64, L1B0);                          \
    BARRIER; PRIO1; MM(0, 1); PRIO0; BARRIER;                                  \
    /* ph7 */                                                                  \
    RDA(1, 1);                                                                 \
    if (!(LAST_)) STG(b1p + (size_t)_ktB * 64, L1B1);                          \
    BARRIER; WAITLGKM0; PRIO1; MM(1, 0); PRIO0; BARRIER;                       \
    /* ph8: counted vmcnt -> buf0 refills landed for next ph1 */               \
    if (!(LAST_)) { STG(a0p + (size_t)_ktB * 64, L1A0); WAITVM6; }             \
    BARRIER; PRIO1; MM(1, 1); PRIO0; BARRIER;                                  \
  }

  int NIT = K >> 7;   // K/128 double-tile iterations (K % 128 == 0)
  for (int i = 0; i < NIT - 1; i++) KBODY(2 * i, 0);
  KBODY(2 * (NIT - 1), 1);
#undef KBODY
#undef MM
#undef RDB
#undef RDA
#undef STG

  // ---------------- epilogue: LDS repack -> coalesced stores ----------------
  // After the final loop barrier the whole 128KB LDS is dead; it splits into
  // 8 x 16KB per-wave-private regions (no barriers needed).
  // C/D frag layout: col=lane&15, row=(lane>>4)*4+reg.
  u16* Rg = &lds[0][0][0] + (size_t)w * 8192;   // this wave's 16KB region
  size_t colbase = n0 + (size_t)wcn * 64;
  if (flags & 2) {
    // bf16 out: region = 128 rows x 64 u16, row-XOR swizzle (r&7)<<3
#pragma unroll
    for (int ni = 0; ni < 4; ni++) {
      int col = ni * 16 + lm;
      float bv = (z == 0) ? bias[colbase + col] : 0.f;
#pragma unroll
      for (int mi = 0; mi < 8; mi++)
#pragma unroll
        for (int j = 0; j < 4; j++) {
          int r = mi * 16 + lq * 4 + j;
          float v = acc[mi][ni][j] + bv;
          if (flags & 1) v = fmaxf(v, 0.f);
          Rg[r * 64 + (col ^ ((r & 7) << 3))] = f2bf(v);
        }
    }
    WAITLGKM0;
    __builtin_amdgcn_sched_barrier(0);
    u16* Cb = (u16*)C + (m0 + (size_t)wr * 128) * N + colbase;
#pragma unroll
    for (int s = 0; s < 16; s++) {
      int r = s * 8 + (l >> 3);
      int slot = (l & 7) ^ (r & 7);
      bf16x8 vv = *(const bf16x8*)&Rg[r * 64 + slot * 8];
      *(bf16x8*)(Cb + (size_t)r * N + (l & 7) * 8) = vv;
    }
  } else {
    // f32 out: two 64-row halves; region = 64 rows x 64 f32, XOR term
    // ((r&3)^((r>>2)&3))<<2 -> conflict-free scatter-write AND row-read
    float* Rf = (float*)Rg;
    float* Cf = (float*)C + (size_t)z * cstride + (m0 + (size_t)wr * 128) * N + colbase;
#pragma unroll
    for (int h = 0; h < 2; h++) {
      if (h) { WAITLGKM0; __builtin_amdgcn_sched_barrier(0); }
#pragma unroll
      for (int ni = 0; ni < 4; ni++) {
        int col = ni * 16 + lm;
        float bv = (z == 0) ? bias[colbase + col] : 0.f;
#pragma unroll
        for (int mh = 0; mh < 4; mh++)
#pragma unroll
          for (int j = 0; j < 4; j++) {
            int mi = h * 4 + mh;
            int r = mh * 16 + lq * 4 + j;               // 0..63 within half
            float v = acc[mi][ni][j] + bv;
            if (flags & 1) v = fmaxf(v, 0.f);
            Rf[r * 64 + (col ^ (((r & 3) ^ ((r >> 2) & 3)) << 2))] = v;
          }
      }
      WAITLGKM0;
      __builtin_amdgcn_sched_barrier(0);
#pragma unroll
      for (int s = 0; s < 16; s++) {
        int r = s * 4 + (l >> 4);
        int slot = (l & 15) ^ ((r & 3) ^ ((r >> 2) & 3));
        f32x4 vv = *(const f32x4*)&Rf[r * 64 + slot * 4];
        *(f32x4*)(Cf + (size_t)(h * 64 + r) * N + (l & 15) * 4) = vv;
      }
    }
  }
}

// ---------------- extract V^T per head: vt[head][d][t] ----------------
__global__ __launch_bounds__(256) void k_vt(const u16* __restrict__ qkv, u16* __restrict__ vt) {
  int head = blockIdx.x;               // b*16+h
  int b = head >> 4, h = head & 15;
  int t0 = blockIdx.y * 64;
  int tid = threadIdx.x;
  __shared__ u16 tile[64][66];
  int c = tid & 63, rr = tid >> 6;
#pragma unroll
  for (int r = 0; r < 16; r++) {
    int tt = r * 4 + rr;
    tile[tt][c] = qkv[(size_t)(b * 1024 + t0 + tt) * 3072 + h * 192 + 128 + c];
  }
  __syncthreads();
#pragma unroll
  for (int r = 0; r < 16; r++) {
    int dd = r * 4 + rr;
    vt[(size_t)head * 65536 + (size_t)dd * 1024 + t0 + c] = tile[c][dd];
  }
}

// ---------------- flash attention, fixed-shift streaming softmax ----------------
__global__ __launch_bounds__(256) void k_attn(const u16* __restrict__ qkv,
    const u16* __restrict__ vt, u16* __restrict__ vals) {
  int head = blockIdx.x;
  int b = head >> 4, h = head & 15;
  int qb = blockIdx.y;
  int tid = threadIdx.x, w = tid >> 6, l = tid & 63;
  int lm = l & 15, lq = l >> 4;
  __shared__ u16 Ks[2][64][32];
  __shared__ u16 Vs[2][64][32];
  __shared__ u16 Ps[4][16][72];
  int q0 = qb * 64 + w * 16;
  const u16* qp = qkv + (size_t)(b * 1024 + q0 + lm) * 3072 + h * 192 + lq * 8;
  bf16x8 qf0 = *(const bf16x8*)qp;
  bf16x8 qf1 = *(const bf16x8*)(qp + 32);
  f32x4 of[4];
#pragma unroll
  for (int d = 0; d < 4; d++) of[d] = (f32x4){0.f, 0.f, 0.f, 0.f};
  float lrow[4] = {0.f, 0.f, 0.f, 0.f};   // per-lane partial denominators
  int srow = w * 16 + (l >> 2);
  int sch = (l & 3) * 8;
  const u16* gk = qkv + (size_t)(b * 1024 + srow) * 3072 + h * 192 + 64 + sch;
  const u16* gv = vt + (size_t)head * 65536 + (size_t)srow * 1024 + sch;
  u16* lk = &Ks[0][0][0] + w * 512 + l * 8;
  u16* lv = &Vs[0][0][0] + w * 512 + l * 8;
  const float CEXP = 0.18033688011112042f;   // log2(e) / sqrt(64)
  for (int t0 = 0; t0 < 1024; t0 += 64) {
    gload16(gk + (size_t)t0 * 3072, lk);
    gload16(gk + (size_t)t0 * 3072 + 32, lk + 64 * 32);
    gload16(gv + t0, lv);
    gload16(gv + t0 + 32, lv + 64 * 32);
    __syncthreads();
#pragma unroll
    for (int c = 0; c < 4; c++) {
      bf16x8 k0f = *(const bf16x8*)&Ks[0][c * 16 + lm][lq * 8];
      bf16x8 k1f = *(const bf16x8*)&Ks[1][c * 16 + lm][lq * 8];
      f32x4 z = (f32x4){0.f, 0.f, 0.f, 0.f};
      z = __builtin_amdgcn_mfma_f32_16x16x32_bf16(qf0, k0f, z, 0, 0, 0);
      z = __builtin_amdgcn_mfma_f32_16x16x32_bf16(qf1, k1f, z, 0, 0, 0);
#pragma unroll
      for (int j = 0; j < 4; j++) {
        float p = __builtin_amdgcn_exp2f(z[j] * CEXP);
        lrow[j] += p;
        Ps[w][lq * 4 + j][c * 16 + lm] = f2bf(p);
      }
    }
    // Ps is wave-private: intra-wave LDS ordering needs no barrier
    bf16x8 pa0 = *(const bf16x8*)&Ps[w][lm][lq * 8];
    bf16x8 pa1 = *(const bf16x8*)&Ps[w][lm][32 + lq * 8];
#pragma unroll
    for (int d = 0; d < 4; d++) {
      bf16x8 v0 = *(const bf16x8*)&Vs[0][d * 16 + lm][lq * 8];
      bf16x8 v1 = *(const bf16x8*)&Vs[1][d * 16 + lm][lq * 8];
      of[d] = __builtin_amdgcn_mfma_f32_16x16x32_bf16(pa0, v0, of[d], 0, 0, 0);
      of[d] = __builtin_amdgcn_mfma_f32_16x16x32_bf16(pa1, v1, of[d], 0, 0, 0);
    }
    __syncthreads();   // protect Ks/Vs before next staging
  }
#pragma unroll
  for (int j = 0; j < 4; j++) {
#pragma unroll
    for (int off = 1; off < 16; off <<= 1) lrow[j] += __shfl_xor(lrow[j], off);
    lrow[j] = 1.f / lrow[j];
  }
#pragma unroll
  for (int d = 0; d < 4; d++)
#pragma unroll
    for (int j = 0; j < 4; j++) {
      int q = q0 + lq * 4 + j;
      vals[(size_t)(b * 1024 + q) * 1024 + h * 64 + d * 16 + lm] =
          f2bf(of[d][j] * lrow[j]);
    }
}

// ---------------- fused residual add (multi-slab) + LayerNorm ----------------
__global__ __launch_bounds__(256) void k_addln(const float* __restrict__ X,
    const float* __restrict__ Y, int nY, size_t ystr,
    const float* __restrict__ gamma, const float* __restrict__ beta,
    float* __restrict__ Xo, u16* __restrict__ Xb) {
  int row = blockIdx.x, tid = threadIdx.x;
  int w = tid >> 6, l = tid & 63;
  int d = tid * 4;
  float4 xv = *(const float4*)(X + (size_t)row * 1024 + d);
  float v0 = xv.x, v1 = xv.y, v2 = xv.z, v3 = xv.w;
  for (int y = 0; y < nY; y++) {
    float4 yv = *(const float4*)(Y + (size_t)y * ystr + (size_t)row * 1024 + d);
    v0 += yv.x; v1 += yv.y; v2 += yv.z; v3 += yv.w;
  }
  float s1 = v0 + v1 + v2 + v3;
  float s2 = v0 * v0 + v1 * v1 + v2 * v2 + v3 * v3;
#pragma unroll
  for (int off = 32; off; off >>= 1) {
    s1 += __shfl_xor(s1, off);
    s2 += __shfl_xor(s2, off);
  }
  __shared__ float red[8];
  if (l == 0) { red[w] = s1; red[4 + w] = s2; }
  __syncthreads();
  s1 = red[0] + red[1] + red[2] + red[3];
  s2 = red[4] + red[5] + red[6] + red[7];
  float mean = s1 * (1.f / 1024.f);
  float var = s2 * (1.f / 1024.f) - mean * mean;
  float rstd = rsqrtf(var + 1e-5f);
  float4 gv = *(const float4*)(gamma + d);
  float4 bv = *(const float4*)(beta + d);
  float o0 = gv.x * (v0 - mean) * rstd + bv.x;
  float o1 = gv.y * (v1 - mean) * rstd + bv.y;
  float o2 = gv.z * (v2 - mean) * rstd + bv.z;
  float o3 = gv.w * (v3 - mean) * rstd + bv.w;
  *(float4*)(Xo + (size_t)row * 1024 + d) = make_float4(o0, o1, o2, o3);
  ushort4 ob; ob.x = f2bf(o0); ob.y = f2bf(o1); ob.z = f2bf(o2); ob.w = f2bf(o3);
  *(ushort4*)(Xb + (size_t)row * 1024 + d) = ob;
}

extern "C" void kernel_launch(void* const* d_in, const int* in_sizes, int n_in,
                              void* d_out, int out_size, void* d_ws, size_t ws_size,
                              hipStream_t stream) {
  const int* tokens  = (const int*)d_in[0];
  const float* emb   = (const float*)d_in[2];
  const float* qkv_w = (const float*)d_in[3];
  const float* qkv_b = (const float*)d_in[4];
  const float* out_w = (const float*)d_in[5];
  const float* out_b = (const float*)d_in[6];
  const float* w1    = (const float*)d_in[7];
  const float* b1    = (const float*)d_in[8];
  const float* w2    = (const float*)d_in[9];
  const float* b2    = (const float*)d_in[10];
  const float* gamma = (const float*)d_in[11];
  const float* beta  = (const float*)d_in[12];

  const size_t MN = (size_t)4096 * 1024;          // elements of one [4096,1024] slab
  bool bigws = ws_size >= (size_t)158334976;

  char* p = (char*)d_ws;
  float* X; u16* Xb; float* Y; u16 *QKV, *VALS, *H1, *VT, *WB;
  u16 *WqkvT, *WoutT, *W1T, *W2T;
  int SPLIT_FFN, SPLIT_OUT;
  if (bigws) {
    X    = (float*)p; p += MN * 4;
    Xb   = (u16*)p;   p += MN * 2;
    H1   = (u16*)p;   p += (size_t)4096 * 4096 * 2;
    Y    = (float*)p; p += MN * 4;                       // Y0
    QKV  = (u16*)p;   p += (size_t)4096 * 3072 * 2;      // Y1,Y2 overlay
    VALS = (u16*)p;   p += MN * 2;                       // Y2 tail overlay
    VT   = (u16*)p;   p += (size_t)64 * 64 * 1024 * 2;   // Y3 overlay
    p += MN * 2;                                         // pad (Y3 tail)
    WB   = (u16*)p;   p += (size_t)12288 * 1024 * 2;     // 4 transposed weights
    WqkvT = WB;
    WoutT = WB + (size_t)3072 * 1024;
    W1T   = WoutT + (size_t)1024 * 1024;
    W2T   = W1T + (size_t)4096 * 1024;
    SPLIT_FFN = 4; SPLIT_OUT = 2;
  } else {
    X    = (float*)p; p += MN * 4;
    Xb   = (u16*)p;   p += MN * 2;
    Y    = (float*)p; p += MN * 4;
    QKV  = (u16*)p;   p += (size_t)4096 * 3072 * 2;
    VALS = (u16*)p;   p += MN * 2;
    H1   = (u16*)p;   p += (size_t)4096 * 4096 * 2;
    VT   = (u16*)p;   p += (size_t)64 * 64 * 1024 * 2;
    WB   = (u16*)p;   p += MN * 2;
    WqkvT = WoutT = W1T = W2T = WB;
    SPLIT_FFN = 2; SPLIT_OUT = 2;
  }

  k_embed<<<4096, 256, 0, stream>>>(tokens, emb, X, Xb);
  for (int i = 0; i < 6; i++) {
    if (bigws) {
      TC4 tc;
      tc.src[0] = qkv_w + (size_t)i * 1024 * 3072; tc.dst[0] = WqkvT;
      tc.K[0] = 1024; tc.N[0] = 3072; tc.start[0] = 0;
      tc.src[1] = out_w + (size_t)i * 1024 * 1024; tc.dst[1] = WoutT;
      tc.K[1] = 1024; tc.N[1] = 1024; tc.start[1] = 3072;
      tc.src[2] = w1 + (size_t)i * 1024 * 4096;    tc.dst[2] = W1T;
      tc.K[2] = 1024; tc.N[2] = 4096; tc.start[2] = 4096;
      tc.src[3] = w2 + (size_t)i * 4096 * 1024;    tc.dst[3] = W2T;
      tc.K[3] = 4096; tc.N[3] = 1024; tc.start[3] = 8192;
      k_tcast4<<<12288, 256, 0, stream>>>(tc);
    } else {
      k_tcast<<<dim3(96, 32), dim3(32, 8), 0, stream>>>(
          qkv_w + (size_t)i * 1024 * 3072, WqkvT, 1024, 3072);
    }
    // QKV projection
    k_gemm256<<<dim3(16, 12, 1), 512, 0, stream>>>(Xb, WqkvT, qkv_b + i * 3072, QKV,
                                                   4096, 3072, 1024, 0, 2);
    // attention
    k_vt<<<dim3(64, 16), 256, 0, stream>>>(QKV, VT);
    k_attn<<<dim3(64, 16), 256, 0, stream>>>(QKV, VT, VALS);
    // output projection (split-K) + add+LN
    if (!bigws)
      k_tcast<<<dim3(32, 32), dim3(32, 8), 0, stream>>>(
          out_w + (size_t)i * 1024 * 1024, WoutT, 1024, 1024);
    k_gemm256<<<dim3(16, 4, SPLIT_OUT), 512, 0, stream>>>(
        VALS, WoutT, out_b + i * 1024, Y, 4096, 1024, 1024 / SPLIT_OUT, MN, 0);
    k_addln<<<4096, 256, 0, stream>>>(X, Y, SPLIT_OUT, MN,
                                      gamma + i * 1024, beta + i * 1024, X, Xb);
    // FFN
    if (!bigws)
      k_tcast<<<dim3(128, 32), dim3(32, 8), 0, stream>>>(
          w1 + (size_t)i * 1024 * 4096, W1T, 1024, 4096);
    k_gemm256<<<dim3(16, 16, 1), 512, 0, stream>>>(Xb, W1T, b1 + i * 4096, H1,
                                                   4096, 4096, 1024, 0, 2 | 1);
    if (!bigws)
      k_tcast<<<dim3(32, 128), dim3(32, 8), 0, stream>>>(
          w2 + (size_t)i * 4096 * 1024, W2T, 4096, 1024);
    k_gemm256<<<dim3(16, 4, SPLIT_FFN), 512, 0, stream>>>(
        H1, W2T, b2 + i * 1024, Y, 4096, 1024, 4096 / SPLIT_FFN, MN, 0);
    float* xdst = (i == 5) ? (float*)d_out : X;
    k_addln<<<4096, 256, 0, stream>>>(X, Y, SPLIT_FFN, MN,
                                      gamma + i * 1024, beta + i * 1024, xdst, Xb);
  }
}